// Round 2
// baseline (810.592 us; speedup 1.0000x reference)
//
#include <hip/hip_runtime.h>
#include <math.h>

#define NB 4
#define NC 128
#define NO 64
#define HH 512
#define WW 512
#define PH 64
#define PW 64
#define PHW (PH*PW)   // 4096

// ---------------- 8x8 max pool (== three 2x2 maxpools) ----------------
// One thread per pooled output element. Consecutive threads -> consecutive
// 32B input segments; two dwordx4 loads per row cover the 8 floats.
__global__ __launch_bounds__(256) void pool8(const float* __restrict__ x,
                                             float* __restrict__ p) {
    int idx = blockIdx.x * 256 + threadIdx.x;   // over NB*NC*PH*PW
    int w  = idx & (PW - 1);
    int h  = (idx >> 6) & (PH - 1);
    int bc = idx >> 12;
    const float* src = x + ((size_t)bc * HH + (size_t)h * 8) * WW + (size_t)w * 8;
    float m = -INFINITY;
#pragma unroll
    for (int r = 0; r < 8; ++r) {
        float4 a = *(const float4*)(src + (size_t)r * WW);
        float4 b = *(const float4*)(src + (size_t)r * WW + 4);
        m = fmaxf(m, fmaxf(fmaxf(a.x, a.y), fmaxf(a.z, a.w)));
        m = fmaxf(m, fmaxf(fmaxf(b.x, b.y), fmaxf(b.z, b.w)));
    }
    p[idx] = m;
}

// ---------------- per-(b,c) spatial sum of p (for vmean) ----------------
__global__ __launch_bounds__(256) void psum_k(const float* __restrict__ p,
                                              float* __restrict__ psum) {
    int bc = blockIdx.x;                 // 0..NB*NC-1
    const float* base = p + (size_t)bc * PHW;
    float s = 0.f;
    for (int i = threadIdx.x; i < PHW; i += 256) s += base[i];
#pragma unroll
    for (int off = 32; off > 0; off >>= 1) s += __shfl_down(s, off, 64);
    __shared__ float ls[4];
    int lane = threadIdx.x & 63, wid = threadIdx.x >> 6;
    if (lane == 0) ls[wid] = s;
    __syncthreads();
    if (threadIdx.x == 0) psum[bc] = ls[0] + ls[1] + ls[2] + ls[3];
}

// ---------------- vmean[b,o] = (sum_c psum[b,c]*Wv[o,c])/4096 + bv[o] ----
__global__ void vmean_k(const float* __restrict__ psum, const float* __restrict__ Wv,
                        const float* __restrict__ bv, float* __restrict__ vmean) {
    int t = threadIdx.x;                 // 256 = NB*NO
    int b = t >> 6, o = t & 63;
    float s = 0.f;
    for (int c = 0; c < NC; ++c) s = fmaf(psum[b * NC + c], Wv[o * NC + c], s);
    vmean[t] = s * (1.f / (float)PHW) + bv[o];
}

// ---------------- attn[b,o,hw] = vmean[b,o] * (sum_c p[b,c,hw]*Wk[o,c] + bk[o])
// Block: (b, o-tile of 16, 256 hw). Wk index is thread-uniform -> scalar loads.
__global__ __launch_bounds__(256) void attn_k(const float* __restrict__ p,
                                              const float* __restrict__ Wk,
                                              const float* __restrict__ bk,
                                              const float* __restrict__ vmean,
                                              float* __restrict__ attn) {
    int blk = blockIdx.x;
    int hwblk = blk & 15;                // 16 hw chunks of 256
    int ot    = (blk >> 4) & 3;          // 4 o-tiles of 16
    int b     = blk >> 6;                // 4 batches
    int hw    = hwblk * 256 + threadIdx.x;
    int obase = ot * 16;
    const float* pb = p + (size_t)b * NC * PHW + hw;
    float acc[16];
#pragma unroll
    for (int o = 0; o < 16; ++o) acc[o] = 0.f;
    for (int c = 0; c < NC; ++c) {
        float val = pb[(size_t)c * PHW];
#pragma unroll
        for (int o = 0; o < 16; ++o)
            acc[o] = fmaf(val, Wk[(obase + o) * NC + c], acc[o]);
    }
#pragma unroll
    for (int o = 0; o < 16; ++o) {
        int oo = obase + o;
        attn[((size_t)(b * NO + oo)) * PHW + hw] =
            vmean[b * NO + oo] * (acc[o] + bk[oo]);
    }
}

// ---------------- bilinear x8 upsample (align_corners=False, edge clamp) ---
// One thread -> 4 consecutive x outputs (float4 store).
__global__ __launch_bounds__(256) void upsample_k(const float* __restrict__ attn,
                                                  float* __restrict__ out) {
    int t  = blockIdx.x * 256 + threadIdx.x;   // over NB*NO*512*128
    int xq = t & 127;
    int y  = (t >> 7) & 511;
    int bo = t >> 16;                          // 0..255
    float sy = (y + 0.5f) * 0.125f - 0.5f;
    float fy0 = floorf(sy);
    float fy = sy - fy0;
    int y0 = (int)fy0;
    int y1 = y0 + 1;
    y0 = max(y0, 0); y1 = min(y1, PH - 1);
    const float* row0 = attn + ((size_t)bo * PH + y0) * PW;
    const float* row1 = attn + ((size_t)bo * PH + y1) * PW;
    float4 res;
    float* rp = (float*)&res;
#pragma unroll
    for (int j = 0; j < 4; ++j) {
        int xx = xq * 4 + j;
        float sx = (xx + 0.5f) * 0.125f - 0.5f;
        float fx0 = floorf(sx);
        float fx = sx - fx0;
        int x0 = (int)fx0;
        int x1 = x0 + 1;
        x0 = max(x0, 0); x1 = min(x1, PW - 1);
        float a00 = row0[x0], a01 = row0[x1];
        float a10 = row1[x0], a11 = row1[x1];
        float top = a00 + fx * (a01 - a00);
        float bot = a10 + fx * (a11 - a10);
        rp[j] = top + fy * (bot - top);
    }
    *(float4*)(out + (size_t)t * 4) = res;
}

extern "C" void kernel_launch(void* const* d_in, const int* in_sizes, int n_in,
                              void* d_out, int out_size, void* d_ws, size_t ws_size,
                              hipStream_t stream) {
    const float* x  = (const float*)d_in[0];
    const float* Wk = (const float*)d_in[1];
    const float* bk = (const float*)d_in[2];
    const float* Wv = (const float*)d_in[3];
    const float* bv = (const float*)d_in[4];
    float* out = (float*)d_out;

    float* p     = (float*)d_ws;                    // NB*NC*PHW   = 2,097,152 f (8 MB)
    float* attn  = p + (size_t)NB * NC * PHW;       // NB*NO*PHW   = 1,048,576 f (4 MB)
    float* psum  = attn + (size_t)NB * NO * PHW;    // 512 f
    float* vmean = psum + NB * NC;                  // 256 f

    pool8<<<NB * NC * PHW / 256, 256, 0, stream>>>(x, p);
    psum_k<<<NB * NC, 256, 0, stream>>>(p, psum);
    vmean_k<<<1, 256, 0, stream>>>(psum, Wv, bv, vmean);
    attn_k<<<256, 256, 0, stream>>>(p, Wk, bk, vmean, attn);
    upsample_k<<<NB * NO * HH * WW / 4 / 256, 256, 0, stream>>>(attn, out);
}